// Round 2
// baseline (503.336 us; speedup 1.0000x reference)
//
#include <hip/hip_runtime.h>
#include <hip/hip_bf16.h>
#include <stdint.h>

#define HIDDEN 1024
#define HEADS 16
#define HD 64
#define BATCH 8
#define SEQ 1024
#define MTOT (BATCH*SEQ)   // 8192 rows total

typedef __attribute__((ext_vector_type(4))) float  f32x4;
typedef __attribute__((ext_vector_type(4))) float  float4v;
typedef __attribute__((ext_vector_type(8))) short  s16x8;
typedef __attribute__((ext_vector_type(4))) short  s16x4;
typedef __bf16 bf16x8 __attribute__((ext_vector_type(8)));

__device__ __forceinline__ short f2bf(float f) {
  uint32_t u = __builtin_bit_cast(uint32_t, f);
  u += 0x7FFFu + ((u >> 16) & 1u);          // RNE to bf16
  return (short)(u >> 16);
}
__device__ __forceinline__ bf16x8 asbf(s16x8 v) {
  return __builtin_bit_cast(bf16x8, v);
}

// ---------------------------------------------------------------------------
// GEMM: C[M=8192][N=1024] = A[M][1024] @ W[N][1024]^T + bias
// A is fp32 (converted on stage) or bf16; C is fp32 or bf16.
// 128x128 tile, BK=32, 4 waves (2x2 of 64x64), mfma_f32_16x16x32_bf16.
// ---------------------------------------------------------------------------
template<bool A_IS_BF16, bool OUT_IS_F32>
__global__ __launch_bounds__(256, 2) void gemm_bt_bias(
    const void* __restrict__ Av, const float* __restrict__ W,
    const float* __restrict__ bias, void* __restrict__ Cv)
{
  __shared__ short Alds[128 * 32];
  __shared__ short Blds[128 * 32];

  const int t  = threadIdx.x;
  const int w  = t >> 6, l = t & 63, g = l >> 4, ln = l & 15;
  const int wr = w >> 1, wc = w & 1;
  const int m0 = blockIdx.x * 128, n0 = blockIdx.y * 128;

  f32x4 acc[4][4];
  #pragma unroll
  for (int i = 0; i < 4; i++)
    #pragma unroll
    for (int j = 0; j < 4; j++) acc[i][j] = (f32x4)0.0f;

  const float* Af = (const float*)Av;
  const short* Ab = (const short*)Av;

  for (int k0 = 0; k0 < 1024; k0 += 32) {
    // ---- stage A tile (128x32) ----
    if constexpr (!A_IS_BF16) {
      #pragma unroll
      for (int i = 0; i < 4; i++) {
        int c = i * 256 + t;                    // 1024 float4 chunks
        int row = c >> 3, c4 = c & 7;
        float4v v = *(const float4v*)(Af + (size_t)(m0 + row) * 1024 + k0 + c4 * 4);
        s16x4 p = { f2bf(v.x), f2bf(v.y), f2bf(v.z), f2bf(v.w) };
        *(s16x4*)(&Alds[row * 32 + c4 * 4]) = p;
      }
    } else {
      #pragma unroll
      for (int i = 0; i < 2; i++) {
        int c = i * 256 + t;                    // 512 short8 chunks
        int row = c >> 2, c8 = c & 3;
        *(s16x8*)(&Alds[row * 32 + c8 * 8]) =
            *(const s16x8*)(Ab + (size_t)(m0 + row) * 1024 + k0 + c8 * 8);
      }
    }
    // ---- stage B tile (W, always fp32) ----
    #pragma unroll
    for (int i = 0; i < 4; i++) {
      int c = i * 256 + t;
      int row = c >> 3, c4 = c & 7;
      float4v v = *(const float4v*)(W + (size_t)(n0 + row) * 1024 + k0 + c4 * 4);
      s16x4 p = { f2bf(v.x), f2bf(v.y), f2bf(v.z), f2bf(v.w) };
      *(s16x4*)(&Blds[row * 32 + c4 * 4]) = p;
    }
    __syncthreads();

    s16x8 af[4], bfr[4];
    #pragma unroll
    for (int mf = 0; mf < 4; mf++)
      af[mf] = *(const s16x8*)(&Alds[(wr * 64 + mf * 16 + ln) * 32 + g * 8]);
    #pragma unroll
    for (int nf = 0; nf < 4; nf++)
      bfr[nf] = *(const s16x8*)(&Blds[(wc * 64 + nf * 16 + ln) * 32 + g * 8]);

    #pragma unroll
    for (int mf = 0; mf < 4; mf++)
      #pragma unroll
      for (int nf = 0; nf < 4; nf++)
        acc[mf][nf] = __builtin_amdgcn_mfma_f32_16x16x32_bf16(
            asbf(af[mf]), asbf(bfr[nf]), acc[mf][nf], 0, 0, 0);
    __syncthreads();
  }

  // ---- epilogue: bias + store ----
  float bv[4];
  #pragma unroll
  for (int nf = 0; nf < 4; nf++) bv[nf] = bias[n0 + wc * 64 + nf * 16 + ln];
  #pragma unroll
  for (int mf = 0; mf < 4; mf++)
    #pragma unroll
    for (int nf = 0; nf < 4; nf++)
      #pragma unroll
      for (int r = 0; r < 4; r++) {
        float vv = acc[mf][nf][r] + bv[nf];
        size_t idx = (size_t)(m0 + wr * 64 + mf * 16 + g * 4 + r) * 1024
                   + n0 + wc * 64 + nf * 16 + ln;
        if constexpr (OUT_IS_F32) ((float*)Cv)[idx] = vv;
        else                      ((short*)Cv)[idx] = f2bf(vv);
      }
}

// ---------------------------------------------------------------------------
// Flash attention: per block = one (b, h, 128 q-rows). 4 waves x 32 q-rows.
// KBLK=64 keys/iter, 16 iters.
//   K: row-major [kk][d], 8-chunk XOR swizzle (conflict-free b128 B-frag reads)
//   V: TRANSPOSED Vt[d][k] with k-chunk XOR swizzle (k ^= 8*((d&7)^(d>>3)))
//      -> conflict-free scalar writes AND conflict-free b128 B-frag reads
//   P: per-wave q-major [32][72] (pad 8) -> scalar writes, b128 A-frag reads
// No tr_b16 / inline asm anywhere; compiler manages all waitcnts. Same-wave
// LDS write->read (P) needs no barrier (in-order LDS per wave).
// ---------------------------------------------------------------------------
__global__ __launch_bounds__(256, 2) void flash_attn(
    const short* __restrict__ Q, const short* __restrict__ K,
    const short* __restrict__ V, short* __restrict__ CTX)
{
  __shared__ short Klds[64 * 64];
  __shared__ short Vt[64 * 64];
  __shared__ short Plds[4][32 * 72];

  const int t  = threadIdx.x;
  const int w  = t >> 6, l = t & 63, g = l >> 4, ln = l & 15;
  const int tile = blockIdx.x & 7;
  const int bh   = blockIdx.x >> 3;
  const int b = bh >> 4, h = bh & 15;
  const size_t rowbase = (size_t)b * SEQ;
  const int colbase = h * HD;
  const int q0w = tile * 128 + w * 32;

  // Q fragments in registers: [mf][kf] -> Q[q0w+mf*16+ln][kf*32 + g*8 .. +7]
  s16x8 qf[2][2];
  #pragma unroll
  for (int mf = 0; mf < 2; mf++)
    #pragma unroll
    for (int kf = 0; kf < 2; kf++)
      qf[mf][kf] = *(const s16x8*)(Q + (rowbase + q0w + mf * 16 + ln) * 1024
                                     + colbase + kf * 32 + g * 8);

  f32x4 acc_o[2][4];
  #pragma unroll
  for (int i = 0; i < 2; i++)
    #pragma unroll
    for (int j = 0; j < 4; j++) acc_o[i][j] = (f32x4)0.0f;

  float m_run[2][4], l_run[2][4];
  #pragma unroll
  for (int i = 0; i < 2; i++)
    #pragma unroll
    for (int r = 0; r < 4; r++) { m_run[i][r] = -1e30f; l_run[i][r] = 0.0f; }

  const float C1 = 0.18033688011112042f;   // log2(e) / sqrt(64)

  for (int kt = 0; kt < 16; kt++) {
    const int kk0 = kt * 64;
    // ---- stage K (swizzled row-major) and V (swizzled transposed) ----
    #pragma unroll
    for (int i = 0; i < 2; i++) {
      int c = i * 256 + t;                 // 512 chunks of 8 bf16
      int kk = c >> 3, dblk = c & 7;
      int dsrc = dblk ^ (kk & 7);
      s16x8 kv = *(const s16x8*)(K + (rowbase + kk0 + kk) * 1024 + colbase + dsrc * 8);
      *(s16x8*)(&Klds[kk * 64 + dblk * 8]) = kv;
      s16x8 vv = *(const s16x8*)(V + (rowbase + kk0 + kk) * 1024 + colbase + dblk * 8);
      #pragma unroll
      for (int e = 0; e < 8; e++) {
        int d  = dblk * 8 + e;
        int sw = (d & 7) ^ (d >> 3);
        Vt[d * 64 + (kk ^ (sw * 8))] = vv[e];
      }
    }
    __syncthreads();

    // ---- QK^T ----
    f32x4 s_acc[2][4];
    #pragma unroll
    for (int i = 0; i < 2; i++)
      #pragma unroll
      for (int j = 0; j < 4; j++) s_acc[i][j] = (f32x4)0.0f;

    #pragma unroll
    for (int kf = 0; kf < 2; kf++) {
      s16x8 kfr[4];
      #pragma unroll
      for (int nf = 0; nf < 4; nf++) {
        int kk = nf * 16 + ln;
        int dblk = kf * 4 + g;
        kfr[nf] = *(const s16x8*)(&Klds[kk * 64 + (dblk ^ (kk & 7)) * 8]);
      }
      #pragma unroll
      for (int mf = 0; mf < 2; mf++)
        #pragma unroll
        for (int nf = 0; nf < 4; nf++)
          s_acc[mf][nf] = __builtin_amdgcn_mfma_f32_16x16x32_bf16(
              asbf(qf[mf][kf]), asbf(kfr[nf]), s_acc[mf][nf], 0, 0, 0);
    }

    // ---- online softmax (wave-parallel, 16-lane shfl reduce) ----
    #pragma unroll
    for (int mf = 0; mf < 2; mf++) {
      #pragma unroll
      for (int r = 0; r < 4; r++) {
        float mx = s_acc[mf][0][r];
        #pragma unroll
        for (int nf = 1; nf < 4; nf++) mx = fmaxf(mx, s_acc[mf][nf][r]);
        mx = fmaxf(mx, __shfl_xor(mx, 1));
        mx = fmaxf(mx, __shfl_xor(mx, 2));
        mx = fmaxf(mx, __shfl_xor(mx, 4));
        mx = fmaxf(mx, __shfl_xor(mx, 8));
        float mnew = fmaxf(m_run[mf][r], mx * C1);
        float sc = exp2f(m_run[mf][r] - mnew);
        m_run[mf][r] = mnew;
        float rs = 0.0f;
        #pragma unroll
        for (int nf = 0; nf < 4; nf++) {
          float pv = exp2f(s_acc[mf][nf][r] * C1 - mnew);
          s_acc[mf][nf][r] = pv;           // reuse as P
          rs += pv;
        }
        rs += __shfl_xor(rs, 1);
        rs += __shfl_xor(rs, 2);
        rs += __shfl_xor(rs, 4);
        rs += __shfl_xor(rs, 8);
        l_run[mf][r] = l_run[mf][r] * sc + rs;
        #pragma unroll
        for (int nf = 0; nf < 4; nf++) acc_o[mf][nf][r] *= sc;
      }
    }

    // ---- write P (bf16) to per-wave q-major padded LDS [32][72] ----
    short* Pw = &Plds[w][0];
    #pragma unroll
    for (int mf = 0; mf < 2; mf++)
      #pragma unroll
      for (int nf = 0; nf < 4; nf++)
        #pragma unroll
        for (int r = 0; r < 4; r++)
          Pw[(mf * 16 + g * 4 + r) * 72 + nf * 16 + ln] = f2bf(s_acc[mf][nf][r]);

    // ---- PV: plain b128 fragment reads (no transpose reads needed) ----
    s16x8 pa[2][2], vb[4][2];
    #pragma unroll
    for (int mf = 0; mf < 2; mf++)
      #pragma unroll
      for (int kf = 0; kf < 2; kf++)
        pa[mf][kf] = *(const s16x8*)(&Pw[(mf * 16 + ln) * 72 + kf * 32 + g * 8]);
    #pragma unroll
    for (int nf = 0; nf < 4; nf++)
      #pragma unroll
      for (int kf = 0; kf < 2; kf++) {
        int d  = nf * 16 + ln;
        int sw = (d & 7) ^ (d >> 3);
        vb[nf][kf] = *(const s16x8*)(&Vt[d * 64 + ((kf * 32 + g * 8) ^ (sw * 8))]);
      }

    #pragma unroll
    for (int kf = 0; kf < 2; kf++)
      #pragma unroll
      for (int mf = 0; mf < 2; mf++)
        #pragma unroll
        for (int nf = 0; nf < 4; nf++)
          acc_o[mf][nf] = __builtin_amdgcn_mfma_f32_16x16x32_bf16(
              asbf(pa[mf][kf]), asbf(vb[nf][kf]), acc_o[mf][nf], 0, 0, 0);
    __syncthreads();
  }

  // ---- finalize: divide by l, store bf16 ctx ----
  #pragma unroll
  for (int mf = 0; mf < 2; mf++)
    #pragma unroll
    for (int r = 0; r < 4; r++) {
      float inv = 1.0f / l_run[mf][r];
      size_t row = rowbase + q0w + mf * 16 + g * 4 + r;
      #pragma unroll
      for (int nf = 0; nf < 4; nf++)
        CTX[row * 1024 + colbase + nf * 16 + ln] = f2bf(acc_o[mf][nf][r] * inv);
    }
}

// ---------------------------------------------------------------------------
extern "C" void kernel_launch(void* const* d_in, const int* in_sizes, int n_in,
                              void* d_out, int out_size, void* d_ws, size_t ws_size,
                              hipStream_t stream) {
  const float* query = (const float*)d_in[0];
  const float* key   = (const float*)d_in[1];
  const float* value = (const float*)d_in[2];
  const float* Wq = (const float*)d_in[3];
  const float* bq = (const float*)d_in[4];
  const float* Wk = (const float*)d_in[5];
  const float* bk = (const float*)d_in[6];
  const float* Wv = (const float*)d_in[7];
  const float* bv = (const float*)d_in[8];
  const float* Wo = (const float*)d_in[9];
  const float* bo = (const float*)d_in[10];

  short* Qb = (short*)d_ws;
  short* Kb = Qb + (size_t)MTOT * 1024;
  short* Vb = Kb + (size_t)MTOT * 1024;
  short* Cx = Vb + (size_t)MTOT * 1024;     // 64 MB total ws use

  dim3 gg(MTOT / 128, HIDDEN / 128), bb(256);
  gemm_bt_bias<false, false><<<gg, bb, 0, stream>>>(query, Wq, bq, Qb);
  gemm_bt_bias<false, false><<<gg, bb, 0, stream>>>(key,   Wk, bk, Kb);
  gemm_bt_bias<false, false><<<gg, bb, 0, stream>>>(value, Wv, bv, Vb);
  flash_attn<<<dim3(BATCH * HEADS * (SEQ / 128)), bb, 0, stream>>>(Qb, Kb, Vb, Cx);
  gemm_bt_bias<true, true><<<gg, bb, 0, stream>>>(Cx, Wo, bo, (float*)d_out);
}

// Round 3
// 264.222 us; speedup vs baseline: 1.9050x; 1.9050x over previous
//
#include <hip/hip_runtime.h>
#include <hip/hip_bf16.h>
#include <stdint.h>

#define HIDDEN 1024
#define HEADS 16
#define HD 64
#define BATCH 8
#define SEQ 1024
#define MTOT (BATCH*SEQ)   // 8192 rows total

typedef __attribute__((ext_vector_type(4))) float  f32x4;
typedef __attribute__((ext_vector_type(4))) float  float4v;
typedef __attribute__((ext_vector_type(8))) short  s16x8;
typedef __attribute__((ext_vector_type(4))) short  s16x4;
typedef __bf16 bf16x8 __attribute__((ext_vector_type(8)));

__device__ __forceinline__ short f2bf(float f) {
  uint32_t u = __builtin_bit_cast(uint32_t, f);
  u += 0x7FFFu + ((u >> 16) & 1u);          // RNE to bf16
  return (short)(u >> 16);
}
__device__ __forceinline__ bf16x8 asbf(s16x8 v) {
  return __builtin_bit_cast(bf16x8, v);
}

// global -> LDS direct DMA, 16 B per lane. LDS dest must be wave-uniform
// (HW adds lane*16); global src is per-lane.
typedef const __attribute__((address_space(1))) void* gvp;
typedef __attribute__((address_space(3)))       void* lvp;
__device__ __forceinline__ void gl_lds16(const void* g, const void* ldsbase) {
  __builtin_amdgcn_global_load_lds((gvp)(uintptr_t)g,
                                   (lvp)(uintptr_t)(uint32_t)(uintptr_t)ldsbase,
                                   16, 0, 0);
}

// ---------------------------------------------------------------------------
// fp32 -> bf16 converters
// ---------------------------------------------------------------------------
__global__ __launch_bounds__(256) void cvt_x(const float* __restrict__ src,
                                             short* __restrict__ dst) {
  int i = blockIdx.x * 256 + threadIdx.x;          // 1,048,576 chunks of 8
  float4v a = *(const float4v*)(src + (size_t)i * 8);
  float4v b = *(const float4v*)(src + (size_t)i * 8 + 4);
  s16x8 o = { f2bf(a.x), f2bf(a.y), f2bf(a.z), f2bf(a.w),
              f2bf(b.x), f2bf(b.y), f2bf(b.z), f2bf(b.w) };
  *(s16x8*)(dst + (size_t)i * 8) = o;
}

__global__ __launch_bounds__(256) void cvt_w(const float* __restrict__ s0,
                                             const float* __restrict__ s1,
                                             const float* __restrict__ s2,
                                             const float* __restrict__ s3,
                                             short* __restrict__ dst) {
  int z = blockIdx.y;
  const float* src = (z == 0) ? s0 : (z == 1) ? s1 : (z == 2) ? s2 : s3;
  int i = blockIdx.x * 256 + threadIdx.x;          // 131,072 chunks of 8
  float4v a = *(const float4v*)(src + (size_t)i * 8);
  float4v b = *(const float4v*)(src + (size_t)i * 8 + 4);
  s16x8 o = { f2bf(a.x), f2bf(a.y), f2bf(a.z), f2bf(a.w),
              f2bf(b.x), f2bf(b.y), f2bf(b.z), f2bf(b.w) };
  *(s16x8*)(dst + (size_t)z * 1048576 + (size_t)i * 8) = o;
}

// ---------------------------------------------------------------------------
// Fast GEMM (bf16 A and W from ws): C[M][1024] = A @ W^T + bias
// m97 structure: 128x128 tile, BK=32, 4 waves, global_load_lds dwordx4.
// ---------------------------------------------------------------------------
template<bool OUT_IS_F32>
__global__ __launch_bounds__(256, 2) void gemm_bf16_dma(
    const short* __restrict__ A, const short* __restrict__ Wb,
    const float* __restrict__ bias, void* __restrict__ Cv)
{
  __shared__ short Alds[128 * 32];
  __shared__ short Blds[128 * 32];

  const int t  = threadIdx.x;
  const int w  = t >> 6, l = t & 63, g = l >> 4, ln = l & 15;
  const int wr = w >> 1, wc = w & 1;
  const int m0 = blockIdx.x * 128, n0 = blockIdx.y * 128;

  f32x4 acc[4][4];
  #pragma unroll
  for (int i = 0; i < 4; i++)
    #pragma unroll
    for (int j = 0; j < 4; j++) acc[i][j] = (f32x4)0.0f;

  for (int k0 = 0; k0 < 1024; k0 += 32) {
    // stage A,B tiles (128x32 bf16 each = 512 chunks of 16B) via LDS-DMA
    #pragma unroll
    for (int i = 0; i < 2; i++) {
      int c = i * 256 + w * 64 + l;                // chunk id, lanes contiguous
      int row = c >> 2, col8 = c & 3;
      gl_lds16(A  + (size_t)(m0 + row) * 1024 + k0 + col8 * 8,
               &Alds[(i * 256 + w * 64) * 8]);
      gl_lds16(Wb + (size_t)(n0 + row) * 1024 + k0 + col8 * 8,
               &Blds[(i * 256 + w * 64) * 8]);
    }
    __syncthreads();

    s16x8 af[4], bfr[4];
    #pragma unroll
    for (int mf = 0; mf < 4; mf++)
      af[mf] = *(const s16x8*)(&Alds[(wr * 64 + mf * 16 + ln) * 32 + g * 8]);
    #pragma unroll
    for (int nf = 0; nf < 4; nf++)
      bfr[nf] = *(const s16x8*)(&Blds[(wc * 64 + nf * 16 + ln) * 32 + g * 8]);

    __builtin_amdgcn_s_setprio(1);
    #pragma unroll
    for (int mf = 0; mf < 4; mf++)
      #pragma unroll
      for (int nf = 0; nf < 4; nf++)
        acc[mf][nf] = __builtin_amdgcn_mfma_f32_16x16x32_bf16(
            asbf(af[mf]), asbf(bfr[nf]), acc[mf][nf], 0, 0, 0);
    __builtin_amdgcn_s_setprio(0);
    __syncthreads();
  }

  float bv[4];
  #pragma unroll
  for (int nf = 0; nf < 4; nf++) bv[nf] = bias[n0 + wc * 64 + nf * 16 + ln];
  #pragma unroll
  for (int mf = 0; mf < 4; mf++)
    #pragma unroll
    for (int nf = 0; nf < 4; nf++)
      #pragma unroll
      for (int r = 0; r < 4; r++) {
        float vv = acc[mf][nf][r] + bv[nf];
        size_t idx = (size_t)(m0 + wr * 64 + mf * 16 + g * 4 + r) * 1024
                   + n0 + wc * 64 + nf * 16 + ln;
        if constexpr (OUT_IS_F32) ((float*)Cv)[idx] = vv;
        else                      ((short*)Cv)[idx] = f2bf(vv);
      }
}

// ---------------------------------------------------------------------------
// Fallback GEMM (round-2): A fp32 or bf16, converted during staging.
// ---------------------------------------------------------------------------
template<bool A_IS_BF16, bool OUT_IS_F32>
__global__ __launch_bounds__(256, 2) void gemm_bt_bias(
    const void* __restrict__ Av, const float* __restrict__ W,
    const float* __restrict__ bias, void* __restrict__ Cv)
{
  __shared__ short Alds[128 * 32];
  __shared__ short Blds[128 * 32];

  const int t  = threadIdx.x;
  const int w  = t >> 6, l = t & 63, g = l >> 4, ln = l & 15;
  const int wr = w >> 1, wc = w & 1;
  const int m0 = blockIdx.x * 128, n0 = blockIdx.y * 128;

  f32x4 acc[4][4];
  #pragma unroll
  for (int i = 0; i < 4; i++)
    #pragma unroll
    for (int j = 0; j < 4; j++) acc[i][j] = (f32x4)0.0f;

  const float* Af = (const float*)Av;
  const short* Ab = (const short*)Av;

  for (int k0 = 0; k0 < 1024; k0 += 32) {
    if constexpr (!A_IS_BF16) {
      #pragma unroll
      for (int i = 0; i < 4; i++) {
        int c = i * 256 + t;
        int row = c >> 3, c4 = c & 7;
        float4v v = *(const float4v*)(Af + (size_t)(m0 + row) * 1024 + k0 + c4 * 4);
        s16x4 p = { f2bf(v.x), f2bf(v.y), f2bf(v.z), f2bf(v.w) };
        *(s16x4*)(&Alds[row * 32 + c4 * 4]) = p;
      }
    } else {
      #pragma unroll
      for (int i = 0; i < 2; i++) {
        int c = i * 256 + t;
        int row = c >> 2, c8 = c & 3;
        *(s16x8*)(&Alds[row * 32 + c8 * 8]) =
            *(const s16x8*)(Ab + (size_t)(m0 + row) * 1024 + k0 + c8 * 8);
      }
    }
    #pragma unroll
    for (int i = 0; i < 4; i++) {
      int c = i * 256 + t;
      int row = c >> 3, c4 = c & 7;
      float4v v = *(const float4v*)(W + (size_t)(n0 + row) * 1024 + k0 + c4 * 4);
      s16x4 p = { f2bf(v.x), f2bf(v.y), f2bf(v.z), f2bf(v.w) };
      *(s16x4*)(&Blds[row * 32 + c4 * 4]) = p;
    }
    __syncthreads();

    s16x8 af[4], bfr[4];
    #pragma unroll
    for (int mf = 0; mf < 4; mf++)
      af[mf] = *(const s16x8*)(&Alds[(wr * 64 + mf * 16 + ln) * 32 + g * 8]);
    #pragma unroll
    for (int nf = 0; nf < 4; nf++)
      bfr[nf] = *(const s16x8*)(&Blds[(wc * 64 + nf * 16 + ln) * 32 + g * 8]);

    #pragma unroll
    for (int mf = 0; mf < 4; mf++)
      #pragma unroll
      for (int nf = 0; nf < 4; nf++)
        acc[mf][nf] = __builtin_amdgcn_mfma_f32_16x16x32_bf16(
            asbf(af[mf]), asbf(bfr[nf]), acc[mf][nf], 0, 0, 0);
    __syncthreads();
  }

  float bv[4];
  #pragma unroll
  for (int nf = 0; nf < 4; nf++) bv[nf] = bias[n0 + wc * 64 + nf * 16 + ln];
  #pragma unroll
  for (int mf = 0; mf < 4; mf++)
    #pragma unroll
    for (int nf = 0; nf < 4; nf++)
      #pragma unroll
      for (int r = 0; r < 4; r++) {
        float vv = acc[mf][nf][r] + bv[nf];
        size_t idx = (size_t)(m0 + wr * 64 + mf * 16 + g * 4 + r) * 1024
                   + n0 + wc * 64 + nf * 16 + ln;
        if constexpr (OUT_IS_F32) ((float*)Cv)[idx] = vv;
        else                      ((short*)Cv)[idx] = f2bf(vv);
      }
}

// ---------------------------------------------------------------------------
// Flash attention (round-2 structure + setprio + defer-max THR=8)
// ---------------------------------------------------------------------------
__global__ __launch_bounds__(256, 2) void flash_attn(
    const short* __restrict__ Q, const short* __restrict__ K,
    const short* __restrict__ V, short* __restrict__ CTX)
{
  __shared__ short Klds[64 * 64];
  __shared__ short Vt[64 * 64];
  __shared__ short Plds[4][32 * 72];

  const int t  = threadIdx.x;
  const int w  = t >> 6, l = t & 63, g = l >> 4, ln = l & 15;
  const int tile = blockIdx.x & 7;
  const int bh   = blockIdx.x >> 3;
  const int b = bh >> 4, h = bh & 15;
  const size_t rowbase = (size_t)b * SEQ;
  const int colbase = h * HD;
  const int q0w = tile * 128 + w * 32;

  s16x8 qf[2][2];
  #pragma unroll
  for (int mf = 0; mf < 2; mf++)
    #pragma unroll
    for (int kf = 0; kf < 2; kf++)
      qf[mf][kf] = *(const s16x8*)(Q + (rowbase + q0w + mf * 16 + ln) * 1024
                                     + colbase + kf * 32 + g * 8);

  f32x4 acc_o[2][4];
  #pragma unroll
  for (int i = 0; i < 2; i++)
    #pragma unroll
    for (int j = 0; j < 4; j++) acc_o[i][j] = (f32x4)0.0f;

  float m_run[2][4], l_run[2][4];
  #pragma unroll
  for (int i = 0; i < 2; i++)
    #pragma unroll
    for (int r = 0; r < 4; r++) { m_run[i][r] = -1e30f; l_run[i][r] = 0.0f; }

  const float C1 = 0.18033688011112042f;   // log2(e) / sqrt(64)

  for (int kt = 0; kt < 16; kt++) {
    const int kk0 = kt * 64;
    #pragma unroll
    for (int i = 0; i < 2; i++) {
      int c = i * 256 + t;
      int kk = c >> 3, dblk = c & 7;
      int dsrc = dblk ^ (kk & 7);
      s16x8 kv = *(const s16x8*)(K + (rowbase + kk0 + kk) * 1024 + colbase + dsrc * 8);
      *(s16x8*)(&Klds[kk * 64 + dblk * 8]) = kv;
      s16x8 vv = *(const s16x8*)(V + (rowbase + kk0 + kk) * 1024 + colbase + dblk * 8);
      #pragma unroll
      for (int e = 0; e < 8; e++) {
        int d  = dblk * 8 + e;
        int sw = (d & 7) ^ (d >> 3);
        Vt[d * 64 + (kk ^ (sw * 8))] = vv[e];
      }
    }
    __syncthreads();

    // ---- QK^T ----
    f32x4 s_acc[2][4];
    #pragma unroll
    for (int i = 0; i < 2; i++)
      #pragma unroll
      for (int j = 0; j < 4; j++) s_acc[i][j] = (f32x4)0.0f;

    __builtin_amdgcn_s_setprio(1);
    #pragma unroll
    for (int kf = 0; kf < 2; kf++) {
      s16x8 kfr[4];
      #pragma unroll
      for (int nf = 0; nf < 4; nf++) {
        int kk = nf * 16 + ln;
        int dblk = kf * 4 + g;
        kfr[nf] = *(const s16x8*)(&Klds[kk * 64 + (dblk ^ (kk & 7)) * 8]);
      }
      #pragma unroll
      for (int mf = 0; mf < 2; mf++)
        #pragma unroll
        for (int nf = 0; nf < 4; nf++)
          s_acc[mf][nf] = __builtin_amdgcn_mfma_f32_16x16x32_bf16(
              asbf(qf[mf][kf]), asbf(kfr[nf]), s_acc[mf][nf], 0, 0, 0);
    }
    __builtin_amdgcn_s_setprio(0);

    // ---- online softmax: row max, then defer-max vote (T13, THR=8) ----
    float smax[2][4];
    float worst = -1e30f;
    #pragma unroll
    for (int mf = 0; mf < 2; mf++)
      #pragma unroll
      for (int r = 0; r < 4; r++) {
        float mx = fmaxf(fmaxf(s_acc[mf][0][r], s_acc[mf][1][r]),
                         fmaxf(s_acc[mf][2][r], s_acc[mf][3][r]));
        mx = fmaxf(mx, __shfl_xor(mx, 1));
        mx = fmaxf(mx, __shfl_xor(mx, 2));
        mx = fmaxf(mx, __shfl_xor(mx, 4));
        mx = fmaxf(mx, __shfl_xor(mx, 8));
        smax[mf][r] = mx * C1;
        worst = fmaxf(worst, smax[mf][r] - m_run[mf][r]);
      }

    if (__all(worst <= 8.0f)) {
      // fast path: keep old max, no rescale of acc_o / l_run
      #pragma unroll
      for (int mf = 0; mf < 2; mf++)
        #pragma unroll
        for (int r = 0; r < 4; r++) {
          float m0v = m_run[mf][r];
          float rs = 0.0f;
          #pragma unroll
          for (int nf = 0; nf < 4; nf++) {
            float pv = exp2f(s_acc[mf][nf][r] * C1 - m0v);
            s_acc[mf][nf][r] = pv;
            rs += pv;
          }
          rs += __shfl_xor(rs, 1);
          rs += __shfl_xor(rs, 2);
          rs += __shfl_xor(rs, 4);
          rs += __shfl_xor(rs, 8);
          l_run[mf][r] += rs;
        }
    } else {
      #pragma unroll
      for (int mf = 0; mf < 2; mf++)
        #pragma unroll
        for (int r = 0; r < 4; r++) {
          float mnew = fmaxf(m_run[mf][r], smax[mf][r]);
          float sc = exp2f(m_run[mf][r] - mnew);
          m_run[mf][r] = mnew;
          float rs = 0.0f;
          #pragma unroll
          for (int nf = 0; nf < 4; nf++) {
            float pv = exp2f(s_acc[mf][nf][r] * C1 - mnew);
            s_acc[mf][nf][r] = pv;
            rs += pv;
          }
          rs += __shfl_xor(rs, 1);
          rs += __shfl_xor(rs, 2);
          rs += __shfl_xor(rs, 4);
          rs += __shfl_xor(rs, 8);
          l_run[mf][r] = l_run[mf][r] * sc + rs;
          #pragma unroll
          for (int nf = 0; nf < 4; nf++) acc_o[mf][nf][r] *= sc;
        }
    }

    // ---- write P (bf16) to per-wave q-major padded LDS [32][72] ----
    short* Pw = &Plds[w][0];
    #pragma unroll
    for (int mf = 0; mf < 2; mf++)
      #pragma unroll
      for (int nf = 0; nf < 4; nf++)
        #pragma unroll
        for (int r = 0; r < 4; r++)
          Pw[(mf * 16 + g * 4 + r) * 72 + nf * 16 + ln] = f2bf(s_acc[mf][nf][r]);

    // ---- PV ----
    s16x8 pa[2][2], vb[4][2];
    #pragma unroll
    for (int mf = 0; mf < 2; mf++)
      #pragma unroll
      for (int kf = 0; kf < 2; kf++)
        pa[mf][kf] = *(const s16x8*)(&Pw[(mf * 16 + ln) * 72 + kf * 32 + g * 8]);
    #pragma unroll
    for (int nf = 0; nf < 4; nf++)
      #pragma unroll
      for (int kf = 0; kf < 2; kf++) {
        int d  = nf * 16 + ln;
        int sw = (d & 7) ^ (d >> 3);
        vb[nf][kf] = *(const s16x8*)(&Vt[d * 64 + ((kf * 32 + g * 8) ^ (sw * 8))]);
      }

    __builtin_amdgcn_s_setprio(1);
    #pragma unroll
    for (int kf = 0; kf < 2; kf++)
      #pragma unroll
      for (int mf = 0; mf < 2; mf++)
        #pragma unroll
        for (int nf = 0; nf < 4; nf++)
          acc_o[mf][nf] = __builtin_amdgcn_mfma_f32_16x16x32_bf16(
              asbf(pa[mf][kf]), asbf(vb[nf][kf]), acc_o[mf][nf], 0, 0, 0);
    __builtin_amdgcn_s_setprio(0);
    __syncthreads();
  }

  #pragma unroll
  for (int mf = 0; mf < 2; mf++)
    #pragma unroll
    for (int r = 0; r < 4; r++) {
      float inv = 1.0f / l_run[mf][r];
      size_t row = rowbase + q0w + mf * 16 + g * 4 + r;
      #pragma unroll
      for (int nf = 0; nf < 4; nf++)
        CTX[row * 1024 + colbase + nf * 16 + ln] = f2bf(acc_o[mf][nf][r] * inv);
    }
}

// ---------------------------------------------------------------------------
extern "C" void kernel_launch(void* const* d_in, const int* in_sizes, int n_in,
                              void* d_out, int out_size, void* d_ws, size_t ws_size,
                              hipStream_t stream) {
  const float* query = (const float*)d_in[0];
  const float* key   = (const float*)d_in[1];
  const float* value = (const float*)d_in[2];
  const float* Wq = (const float*)d_in[3];
  const float* bq = (const float*)d_in[4];
  const float* Wk = (const float*)d_in[5];
  const float* bk = (const float*)d_in[6];
  const float* Wv = (const float*)d_in[7];
  const float* bv = (const float*)d_in[8];
  const float* Wo = (const float*)d_in[9];
  const float* bo = (const float*)d_in[10];

  const size_t E = (size_t)MTOT * 1024;     // 8,388,608 elements
  short* Qb = (short*)d_ws;
  short* Kb = Qb + E;
  short* Vb = Kb + E;
  short* Cx = Vb + E;
  short* T  = Cx + E;                        // ping-pong bf16 input buffer
  short* Wb = T  + E;                        // 4x (1024x1024) bf16 weights

  const size_t need = (5 * E + 4ull * 1048576) * 2;   // ~92.3 MB
  dim3 gg(MTOT / 128, HIDDEN / 128), bb(256);
  dim3 fg(BATCH * HEADS * (SEQ / 128));

  if (ws_size >= need) {
    cvt_w<<<dim3(512, 4), bb, 0, stream>>>(Wq, Wk, Wv, Wo, Wb);
    cvt_x<<<4096, bb, 0, stream>>>(query, T);
    gemm_bf16_dma<false><<<gg, bb, 0, stream>>>(T, Wb + 0 * 1048576, bq, Qb);
    cvt_x<<<4096, bb, 0, stream>>>(key, T);
    gemm_bf16_dma<false><<<gg, bb, 0, stream>>>(T, Wb + 1 * 1048576, bk, Kb);
    cvt_x<<<4096, bb, 0, stream>>>(value, T);
    gemm_bf16_dma<false><<<gg, bb, 0, stream>>>(T, Wb + 2 * 1048576, bv, Vb);
    flash_attn<<<fg, bb, 0, stream>>>(Qb, Kb, Vb, Cx);
    gemm_bf16_dma<true><<<gg, bb, 0, stream>>>(Cx, Wb + 3 * 1048576, bo, (float*)d_out);
  } else {
    gemm_bt_bias<false, false><<<gg, bb, 0, stream>>>(query, Wq, bq, Qb);
    gemm_bt_bias<false, false><<<gg, bb, 0, stream>>>(key,   Wk, bk, Kb);
    gemm_bt_bias<false, false><<<gg, bb, 0, stream>>>(value, Wv, bv, Vb);
    flash_attn<<<fg, bb, 0, stream>>>(Qb, Kb, Vb, Cx);
    gemm_bt_bias<true, true><<<gg, bb, 0, stream>>>(Cx, Wo, bo, (float*)d_out);
  }
}

// Round 4
// 241.318 us; speedup vs baseline: 2.0858x; 1.0949x over previous
//
#include <hip/hip_runtime.h>
#include <hip/hip_bf16.h>
#include <stdint.h>

#define HIDDEN 1024
#define HEADS 16
#define HD 64
#define BATCH 8
#define SEQ 1024
#define MTOT (BATCH*SEQ)   // 8192 rows total

typedef __attribute__((ext_vector_type(4))) float  f32x4;
typedef __attribute__((ext_vector_type(4))) float  float4v;
typedef __attribute__((ext_vector_type(8))) short  s16x8;
typedef __attribute__((ext_vector_type(4))) short  s16x4;
typedef __bf16 bf16x8 __attribute__((ext_vector_type(8)));

__device__ __forceinline__ short f2bf(float f) {
  uint32_t u = __builtin_bit_cast(uint32_t, f);
  u += 0x7FFFu + ((u >> 16) & 1u);          // RNE to bf16
  return (short)(u >> 16);
}
__device__ __forceinline__ bf16x8 asbf(s16x8 v) {
  return __builtin_bit_cast(bf16x8, v);
}

// ---- DPP 16-lane reductions (VALU only, no LDS swizzle) -------------------
// quad_perm[1,0,3,2]=0xB1 (xor1), quad_perm[2,3,0,1]=0x4E (xor2),
// row_half_mirror=0x141 (pairs opposite quads), row_mirror=0x140 (halves).
__device__ __forceinline__ float dpp_fmax16(float x) {
  int t;
  t = __builtin_amdgcn_update_dpp(0, __builtin_bit_cast(int, x), 0xB1, 0xF, 0xF, true);
  x = fmaxf(x, __builtin_bit_cast(float, t));
  t = __builtin_amdgcn_update_dpp(0, __builtin_bit_cast(int, x), 0x4E, 0xF, 0xF, true);
  x = fmaxf(x, __builtin_bit_cast(float, t));
  t = __builtin_amdgcn_update_dpp(0, __builtin_bit_cast(int, x), 0x141, 0xF, 0xF, true);
  x = fmaxf(x, __builtin_bit_cast(float, t));
  t = __builtin_amdgcn_update_dpp(0, __builtin_bit_cast(int, x), 0x140, 0xF, 0xF, true);
  x = fmaxf(x, __builtin_bit_cast(float, t));
  return x;
}
__device__ __forceinline__ float dpp_fadd16(float x) {
  int t;
  t = __builtin_amdgcn_update_dpp(0, __builtin_bit_cast(int, x), 0xB1, 0xF, 0xF, true);
  x += __builtin_bit_cast(float, t);
  t = __builtin_amdgcn_update_dpp(0, __builtin_bit_cast(int, x), 0x4E, 0xF, 0xF, true);
  x += __builtin_bit_cast(float, t);
  t = __builtin_amdgcn_update_dpp(0, __builtin_bit_cast(int, x), 0x141, 0xF, 0xF, true);
  x += __builtin_bit_cast(float, t);
  t = __builtin_amdgcn_update_dpp(0, __builtin_bit_cast(int, x), 0x140, 0xF, 0xF, true);
  x += __builtin_bit_cast(float, t);
  return x;
}

// global -> LDS direct DMA, 16 B per lane.
typedef const __attribute__((address_space(1))) void* gvp;
typedef __attribute__((address_space(3)))       void* lvp;
__device__ __forceinline__ void gl_lds16(const void* g, const void* ldsbase) {
  __builtin_amdgcn_global_load_lds((gvp)(uintptr_t)g,
                                   (lvp)(uintptr_t)(uint32_t)(uintptr_t)ldsbase,
                                   16, 0, 0);
}

// ---------------------------------------------------------------------------
// fp32 -> bf16 converters
// ---------------------------------------------------------------------------
__global__ __launch_bounds__(256) void cvt_x(const float* __restrict__ src,
                                             short* __restrict__ dst) {
  int i = blockIdx.x * 256 + threadIdx.x;
  float4v a = *(const float4v*)(src + (size_t)i * 8);
  float4v b = *(const float4v*)(src + (size_t)i * 8 + 4);
  s16x8 o = { f2bf(a.x), f2bf(a.y), f2bf(a.z), f2bf(a.w),
              f2bf(b.x), f2bf(b.y), f2bf(b.z), f2bf(b.w) };
  *(s16x8*)(dst + (size_t)i * 8) = o;
}

__global__ __launch_bounds__(256) void cvt_w(const float* __restrict__ s0,
                                             const float* __restrict__ s1,
                                             const float* __restrict__ s2,
                                             const float* __restrict__ s3,
                                             short* __restrict__ dst) {
  int z = blockIdx.y;
  const float* src = (z == 0) ? s0 : (z == 1) ? s1 : (z == 2) ? s2 : s3;
  int i = blockIdx.x * 256 + threadIdx.x;
  float4v a = *(const float4v*)(src + (size_t)i * 8);
  float4v b = *(const float4v*)(src + (size_t)i * 8 + 4);
  s16x8 o = { f2bf(a.x), f2bf(a.y), f2bf(a.z), f2bf(a.w),
              f2bf(b.x), f2bf(b.y), f2bf(b.z), f2bf(b.w) };
  *(s16x8*)(dst + (size_t)z * 1048576 + (size_t)i * 8) = o;
}

// ---------------------------------------------------------------------------
// Fast GEMM (bf16 A and W from ws): C[M][1024] = A @ W^T + bias
// ---------------------------------------------------------------------------
template<bool OUT_IS_F32>
__global__ __launch_bounds__(256, 2) void gemm_bf16_dma(
    const short* __restrict__ A, const short* __restrict__ Wb,
    const float* __restrict__ bias, void* __restrict__ Cv)
{
  __shared__ short Alds[128 * 32];
  __shared__ short Blds[128 * 32];

  const int t  = threadIdx.x;
  const int w  = t >> 6, l = t & 63, g = l >> 4, ln = l & 15;
  const int wr = w >> 1, wc = w & 1;
  const int m0 = blockIdx.x * 128, n0 = blockIdx.y * 128;

  f32x4 acc[4][4];
  #pragma unroll
  for (int i = 0; i < 4; i++)
    #pragma unroll
    for (int j = 0; j < 4; j++) acc[i][j] = (f32x4)0.0f;

  for (int k0 = 0; k0 < 1024; k0 += 32) {
    #pragma unroll
    for (int i = 0; i < 2; i++) {
      int c = i * 256 + w * 64 + l;
      int row = c >> 2, col8 = c & 3;
      gl_lds16(A  + (size_t)(m0 + row) * 1024 + k0 + col8 * 8,
               &Alds[(i * 256 + w * 64) * 8]);
      gl_lds16(Wb + (size_t)(n0 + row) * 1024 + k0 + col8 * 8,
               &Blds[(i * 256 + w * 64) * 8]);
    }
    __syncthreads();

    s16x8 af[4], bfr[4];
    #pragma unroll
    for (int mf = 0; mf < 4; mf++)
      af[mf] = *(const s16x8*)(&Alds[(wr * 64 + mf * 16 + ln) * 32 + g * 8]);
    #pragma unroll
    for (int nf = 0; nf < 4; nf++)
      bfr[nf] = *(const s16x8*)(&Blds[(wc * 64 + nf * 16 + ln) * 32 + g * 8]);

    __builtin_amdgcn_s_setprio(1);
    #pragma unroll
    for (int mf = 0; mf < 4; mf++)
      #pragma unroll
      for (int nf = 0; nf < 4; nf++)
        acc[mf][nf] = __builtin_amdgcn_mfma_f32_16x16x32_bf16(
            asbf(af[mf]), asbf(bfr[nf]), acc[mf][nf], 0, 0, 0);
    __builtin_amdgcn_s_setprio(0);
    __syncthreads();
  }

  float bv[4];
  #pragma unroll
  for (int nf = 0; nf < 4; nf++) bv[nf] = bias[n0 + wc * 64 + nf * 16 + ln];
  #pragma unroll
  for (int mf = 0; mf < 4; mf++)
    #pragma unroll
    for (int nf = 0; nf < 4; nf++)
      #pragma unroll
      for (int r = 0; r < 4; r++) {
        float vv = acc[mf][nf][r] + bv[nf];
        size_t idx = (size_t)(m0 + wr * 64 + mf * 16 + g * 4 + r) * 1024
                   + n0 + wc * 64 + nf * 16 + ln;
        if constexpr (OUT_IS_F32) ((float*)Cv)[idx] = vv;
        else                      ((short*)Cv)[idx] = f2bf(vv);
      }
}

// ---------------------------------------------------------------------------
// Fallback GEMM (round-2): A fp32 or bf16, converted during staging.
// ---------------------------------------------------------------------------
template<bool A_IS_BF16, bool OUT_IS_F32>
__global__ __launch_bounds__(256, 2) void gemm_bt_bias(
    const void* __restrict__ Av, const float* __restrict__ W,
    const float* __restrict__ bias, void* __restrict__ Cv)
{
  __shared__ short Alds[128 * 32];
  __shared__ short Blds[128 * 32];

  const int t  = threadIdx.x;
  const int w  = t >> 6, l = t & 63, g = l >> 4, ln = l & 15;
  const int wr = w >> 1, wc = w & 1;
  const int m0 = blockIdx.x * 128, n0 = blockIdx.y * 128;

  f32x4 acc[4][4];
  #pragma unroll
  for (int i = 0; i < 4; i++)
    #pragma unroll
    for (int j = 0; j < 4; j++) acc[i][j] = (f32x4)0.0f;

  const float* Af = (const float*)Av;
  const short* Ab = (const short*)Av;

  for (int k0 = 0; k0 < 1024; k0 += 32) {
    if constexpr (!A_IS_BF16) {
      #pragma unroll
      for (int i = 0; i < 4; i++) {
        int c = i * 256 + t;
        int row = c >> 3, c4 = c & 7;
        float4v v = *(const float4v*)(Af + (size_t)(m0 + row) * 1024 + k0 + c4 * 4);
        s16x4 p = { f2bf(v.x), f2bf(v.y), f2bf(v.z), f2bf(v.w) };
        *(s16x4*)(&Alds[row * 32 + c4 * 4]) = p;
      }
    } else {
      #pragma unroll
      for (int i = 0; i < 2; i++) {
        int c = i * 256 + t;
        int row = c >> 2, c8 = c & 3;
        *(s16x8*)(&Alds[row * 32 + c8 * 8]) =
            *(const s16x8*)(Ab + (size_t)(m0 + row) * 1024 + k0 + c8 * 8);
      }
    }
    #pragma unroll
    for (int i = 0; i < 4; i++) {
      int c = i * 256 + t;
      int row = c >> 3, c4 = c & 7;
      float4v v = *(const float4v*)(W + (size_t)(n0 + row) * 1024 + k0 + c4 * 4);
      s16x4 p = { f2bf(v.x), f2bf(v.y), f2bf(v.z), f2bf(v.w) };
      *(s16x4*)(&Blds[row * 32 + c4 * 4]) = p;
    }
    __syncthreads();

    s16x8 af[4], bfr[4];
    #pragma unroll
    for (int mf = 0; mf < 4; mf++)
      af[mf] = *(const s16x8*)(&Alds[(wr * 64 + mf * 16 + ln) * 32 + g * 8]);
    #pragma unroll
    for (int nf = 0; nf < 4; nf++)
      bfr[nf] = *(const s16x8*)(&Blds[(wc * 64 + nf * 16 + ln) * 32 + g * 8]);

    #pragma unroll
    for (int mf = 0; mf < 4; mf++)
      #pragma unroll
      for (int nf = 0; nf < 4; nf++)
        acc[mf][nf] = __builtin_amdgcn_mfma_f32_16x16x32_bf16(
            asbf(af[mf]), asbf(bfr[nf]), acc[mf][nf], 0, 0, 0);
    __syncthreads();
  }

  float bv[4];
  #pragma unroll
  for (int nf = 0; nf < 4; nf++) bv[nf] = bias[n0 + wc * 64 + nf * 16 + ln];
  #pragma unroll
  for (int mf = 0; mf < 4; mf++)
    #pragma unroll
    for (int nf = 0; nf < 4; nf++)
      #pragma unroll
      for (int r = 0; r < 4; r++) {
        float vv = acc[mf][nf][r] + bv[nf];
        size_t idx = (size_t)(m0 + wr * 64 + mf * 16 + g * 4 + r) * 1024
                   + n0 + wc * 64 + nf * 16 + ln;
        if constexpr (OUT_IS_F32) ((float*)Cv)[idx] = vv;
        else                      ((short*)Cv)[idx] = f2bf(vv);
      }
}

// ---------------------------------------------------------------------------
// Flash attention: DPP softmax reductions + swizzled P buffer.
//   P swizzle: store col^(((row>>2)&3)<<3); per write-instr that equals g<<3
//   -> 4 disjoint 8-bank windows (all 32 banks). Reads: 8-col blocks stay
//   contiguous, block index (kf*4+g)^(ln>>2), 16B-aligned.
// ---------------------------------------------------------------------------
__global__ __launch_bounds__(256, 2) void flash_attn(
    const short* __restrict__ Q, const short* __restrict__ K,
    const short* __restrict__ V, short* __restrict__ CTX)
{
  __shared__ short Klds[64 * 64];
  __shared__ short Vt[64 * 64];
  __shared__ short Plds[4][32 * 72];

  const int t  = threadIdx.x;
  const int w  = t >> 6, l = t & 63, g = l >> 4, ln = l & 15;
  const int tile = blockIdx.x & 7;
  const int bh   = blockIdx.x >> 3;
  const int b = bh >> 4, h = bh & 15;
  const size_t rowbase = (size_t)b * SEQ;
  const int colbase = h * HD;
  const int q0w = tile * 128 + w * 32;

  s16x8 qf[2][2];
  #pragma unroll
  for (int mf = 0; mf < 2; mf++)
    #pragma unroll
    for (int kf = 0; kf < 2; kf++)
      qf[mf][kf] = *(const s16x8*)(Q + (rowbase + q0w + mf * 16 + ln) * 1024
                                     + colbase + kf * 32 + g * 8);

  f32x4 acc_o[2][4];
  #pragma unroll
  for (int i = 0; i < 2; i++)
    #pragma unroll
    for (int j = 0; j < 4; j++) acc_o[i][j] = (f32x4)0.0f;

  float m_run[2][4], l_run[2][4];
  #pragma unroll
  for (int i = 0; i < 2; i++)
    #pragma unroll
    for (int r = 0; r < 4; r++) { m_run[i][r] = -1e30f; l_run[i][r] = 0.0f; }

  const float C1 = 0.18033688011112042f;   // log2(e) / sqrt(64)

  for (int kt = 0; kt < 16; kt++) {
    const int kk0 = kt * 64;
    #pragma unroll
    for (int i = 0; i < 2; i++) {
      int c = i * 256 + t;
      int kk = c >> 3, dblk = c & 7;
      int dsrc = dblk ^ (kk & 7);
      s16x8 kv = *(const s16x8*)(K + (rowbase + kk0 + kk) * 1024 + colbase + dsrc * 8);
      *(s16x8*)(&Klds[kk * 64 + dblk * 8]) = kv;
      s16x8 vv = *(const s16x8*)(V + (rowbase + kk0 + kk) * 1024 + colbase + dblk * 8);
      #pragma unroll
      for (int e = 0; e < 8; e++) {
        int d  = dblk * 8 + e;
        int sw = (d & 7) ^ (d >> 3);
        Vt[d * 64 + (kk ^ (sw * 8))] = vv[e];
      }
    }
    __syncthreads();

    // ---- QK^T ----
    f32x4 s_acc[2][4];
    #pragma unroll
    for (int i = 0; i < 2; i++)
      #pragma unroll
      for (int j = 0; j < 4; j++) s_acc[i][j] = (f32x4)0.0f;

    __builtin_amdgcn_s_setprio(1);
    #pragma unroll
    for (int kf = 0; kf < 2; kf++) {
      s16x8 kfr[4];
      #pragma unroll
      for (int nf = 0; nf < 4; nf++) {
        int kk = nf * 16 + ln;
        int dblk = kf * 4 + g;
        kfr[nf] = *(const s16x8*)(&Klds[kk * 64 + (dblk ^ (kk & 7)) * 8]);
      }
      #pragma unroll
      for (int mf = 0; mf < 2; mf++)
        #pragma unroll
        for (int nf = 0; nf < 4; nf++)
          s_acc[mf][nf] = __builtin_amdgcn_mfma_f32_16x16x32_bf16(
              asbf(qf[mf][kf]), asbf(kfr[nf]), s_acc[mf][nf], 0, 0, 0);
    }
    __builtin_amdgcn_s_setprio(0);

    // ---- online softmax with DPP reductions + defer-max (THR=8) ----
    float smax[2][4];
    float worst = -1e30f;
    #pragma unroll
    for (int mf = 0; mf < 2; mf++)
      #pragma unroll
      for (int r = 0; r < 4; r++) {
        float mx = fmaxf(fmaxf(s_acc[mf][0][r], s_acc[mf][1][r]),
                         fmaxf(s_acc[mf][2][r], s_acc[mf][3][r]));
        mx = dpp_fmax16(mx);
        smax[mf][r] = mx * C1;
        worst = fmaxf(worst, smax[mf][r] - m_run[mf][r]);
      }

    if (__all(worst <= 8.0f)) {
      #pragma unroll
      for (int mf = 0; mf < 2; mf++)
        #pragma unroll
        for (int r = 0; r < 4; r++) {
          float m0v = m_run[mf][r];
          float rs = 0.0f;
          #pragma unroll
          for (int nf = 0; nf < 4; nf++) {
            float pv = exp2f(s_acc[mf][nf][r] * C1 - m0v);
            s_acc[mf][nf][r] = pv;
            rs += pv;
          }
          l_run[mf][r] += dpp_fadd16(rs);
        }
    } else {
      #pragma unroll
      for (int mf = 0; mf < 2; mf++)
        #pragma unroll
        for (int r = 0; r < 4; r++) {
          float mnew = fmaxf(m_run[mf][r], smax[mf][r]);
          float sc = exp2f(m_run[mf][r] - mnew);
          m_run[mf][r] = mnew;
          float rs = 0.0f;
          #pragma unroll
          for (int nf = 0; nf < 4; nf++) {
            float pv = exp2f(s_acc[mf][nf][r] * C1 - mnew);
            s_acc[mf][nf][r] = pv;
            rs += pv;
          }
          l_run[mf][r] = l_run[mf][r] * sc + dpp_fadd16(rs);
          #pragma unroll
          for (int nf = 0; nf < 4; nf++) acc_o[mf][nf][r] *= sc;
        }
    }

    // ---- write P (bf16) to per-wave swizzled LDS [32][72] ----
    short* Pw = &Plds[w][0];
    #pragma unroll
    for (int mf = 0; mf < 2; mf++)
      #pragma unroll
      for (int nf = 0; nf < 4; nf++)
        #pragma unroll
        for (int r = 0; r < 4; r++) {
          int row = mf * 16 + g * 4 + r;
          int colS = (nf * 16 + ln) ^ (g << 3);      // ((row>>2)&3)<<3 == g<<3
          Pw[row * 72 + colS] = f2bf(s_acc[mf][nf][r]);
        }

    // ---- PV ----
    s16x8 pa[2][2], vb[4][2];
    #pragma unroll
    for (int mf = 0; mf < 2; mf++)
      #pragma unroll
      for (int kf = 0; kf < 2; kf++)
        pa[mf][kf] = *(const s16x8*)(
            &Pw[(mf * 16 + ln) * 72 + (((kf * 4 + g) ^ (ln >> 2)) << 3)]);
    #pragma unroll
    for (int nf = 0; nf < 4; nf++)
      #pragma unroll
      for (int kf = 0; kf < 2; kf++) {
        int d  = nf * 16 + ln;
        int sw = (d & 7) ^ (d >> 3);
        vb[nf][kf] = *(const s16x8*)(&Vt[d * 64 + ((kf * 32 + g * 8) ^ (sw * 8))]);
      }

    __builtin_amdgcn_s_setprio(1);
    #pragma unroll
    for (int kf = 0; kf < 2; kf++)
      #pragma unroll
      for (int mf = 0; mf < 2; mf++)
        #pragma unroll
        for (int nf = 0; nf < 4; nf++)
          acc_o[mf][nf] = __builtin_amdgcn_mfma_f32_16x16x32_bf16(
              asbf(pa[mf][kf]), asbf(vb[nf][kf]), acc_o[mf][nf], 0, 0, 0);
    __builtin_amdgcn_s_setprio(0);
    __syncthreads();
  }

  #pragma unroll
  for (int mf = 0; mf < 2; mf++)
    #pragma unroll
    for (int r = 0; r < 4; r++) {
      float inv = 1.0f / l_run[mf][r];
      size_t row = rowbase + q0w + mf * 16 + g * 4 + r;
      #pragma unroll
      for (int nf = 0; nf < 4; nf++)
        CTX[row * 1024 + colbase + nf * 16 + ln] = f2bf(acc_o[mf][nf][r] * inv);
    }
}

// ---------------------------------------------------------------------------
extern "C" void kernel_launch(void* const* d_in, const int* in_sizes, int n_in,
                              void* d_out, int out_size, void* d_ws, size_t ws_size,
                              hipStream_t stream) {
  const float* query = (const float*)d_in[0];
  const float* key   = (const float*)d_in[1];
  const float* value = (const float*)d_in[2];
  const float* Wq = (const float*)d_in[3];
  const float* bq = (const float*)d_in[4];
  const float* Wk = (const float*)d_in[5];
  const float* bk = (const float*)d_in[6];
  const float* Wv = (const float*)d_in[7];
  const float* bv = (const float*)d_in[8];
  const float* Wo = (const float*)d_in[9];
  const float* bo = (const float*)d_in[10];

  const size_t E = (size_t)MTOT * 1024;
  short* Qb = (short*)d_ws;
  short* Kb = Qb + E;
  short* Vb = Kb + E;
  short* Cx = Vb + E;
  short* T  = Cx + E;
  short* Wb = T  + E;

  const size_t need = (5 * E + 4ull * 1048576) * 2;   // ~92.3 MB
  dim3 gg(MTOT / 128, HIDDEN / 128), bb(256);
  dim3 fg(BATCH * HEADS * (SEQ / 128));

  if (ws_size >= need) {
    cvt_w<<<dim3(512, 4), bb, 0, stream>>>(Wq, Wk, Wv, Wo, Wb);
    cvt_x<<<4096, bb, 0, stream>>>(query, T);
    gemm_bf16_dma<false><<<gg, bb, 0, stream>>>(T, Wb + 0 * 1048576, bq, Qb);
    cvt_x<<<4096, bb, 0, stream>>>(key, T);
    gemm_bf16_dma<false><<<gg, bb, 0, stream>>>(T, Wb + 1 * 1048576, bk, Kb);
    cvt_x<<<4096, bb, 0, stream>>>(value, T);
    gemm_bf16_dma<false><<<gg, bb, 0, stream>>>(T, Wb + 2 * 1048576, bv, Vb);
    flash_attn<<<fg, bb, 0, stream>>>(Qb, Kb, Vb, Cx);
    gemm_bf16_dma<true><<<gg, bb, 0, stream>>>(Cx, Wb + 3 * 1048576, bo, (float*)d_out);
  } else {
    gemm_bt_bias<false, false><<<gg, bb, 0, stream>>>(query, Wq, bq, Qb);
    gemm_bt_bias<false, false><<<gg, bb, 0, stream>>>(key,   Wk, bk, Kb);
    gemm_bt_bias<false, false><<<gg, bb, 0, stream>>>(value, Wv, bv, Vb);
    flash_attn<<<fg, bb, 0, stream>>>(Qb, Kb, Vb, Cx);
    gemm_bt_bias<true, true><<<gg, bb, 0, stream>>>(Cx, Wo, bo, (float*)d_out);
  }
}